// Round 6
// baseline (323.786 us; speedup 1.0000x reference)
//
#include <hip/hip_runtime.h>

typedef __bf16 bf16;
typedef __attribute__((ext_vector_type(4))) __bf16 bf16x4;
typedef __attribute__((ext_vector_type(8))) __bf16 bf16x8;
typedef __attribute__((ext_vector_type(4))) float f32x4;

#define MFMA16(a, b, c) __builtin_amdgcn_mfma_f32_16x16x32_bf16((a), (b), (c), 0, 0, 0)

constexpr int BM  = 128;
constexpr int BK  = 64;
constexpr int LDT = 72;  // padded LDS row stride in bf16 (144 B = 9*16 B: 16B-aligned, bank-spread)

constexpr int N    = 8192;
constexpr int FEAT = 256;
constexpr int HID  = 64;
constexpr int KSPLIT = 8;

// Cpart[blockIdx.y][M][64] = A[M][Kslice] (f32, cvt->bf16 on stage) @ Bt[64][Kslice]^T (bf16)
// grid = (M/BM, ksplit); plain stores into owned partial slabs, no atomics.
__global__ __launch_bounds__(256) void gcn_mm(const float* __restrict__ A, int K,
                                              const bf16* __restrict__ Bt,
                                              float* __restrict__ Cpart, int ktiles) {
  __shared__ bf16 As[BM * LDT];
  __shared__ bf16 Bs[64 * LDT];
  const int tid = threadIdx.x;
  const int lane = tid & 63;
  const int wave = tid >> 6;
  const int i0 = blockIdx.x * BM;
  const int kbase = blockIdx.y * ktiles * BK;

  f32x4 acc[2][4] = {};

  for (int kt = 0; kt < ktiles; ++kt) {
    const int k0 = kbase + kt * BK;
    {  // stage A tile [128][64] f32 -> bf16
      const int rr = tid >> 4, c4 = tid & 15;
#pragma unroll
      for (int s = 0; s < 8; ++s) {
        const int row = rr + s * 16;
        const float4 v = *reinterpret_cast<const float4*>(&A[(size_t)(i0 + row) * K + k0 + c4 * 4]);
        bf16x4 o;
        o[0] = (bf16)v.x; o[1] = (bf16)v.y; o[2] = (bf16)v.z; o[3] = (bf16)v.w;
        *reinterpret_cast<bf16x4*>(&As[row * LDT + c4 * 4]) = o;
      }
    }
    {  // stage B tile [64][64] bf16 ([N][K] layout)
      const int idx = tid * 2;
      const int n = idx >> 3, q = idx & 7;
      *reinterpret_cast<bf16x8*>(&Bs[n * LDT + q * 8]) =
          *reinterpret_cast<const bf16x8*>(&Bt[(size_t)n * K + k0 + q * 8]);
      *reinterpret_cast<bf16x8*>(&Bs[n * LDT + (q + 1) * 8]) =
          *reinterpret_cast<const bf16x8*>(&Bt[(size_t)n * K + k0 + (q + 1) * 8]);
    }
    __syncthreads();
    const int rA = wave * 32 + (lane & 15);
#pragma unroll
    for (int kk = 0; kk < 2; ++kk) {
      const int kb = kk * 32 + ((lane >> 4) << 3);
      const bf16x8 a0 = *reinterpret_cast<const bf16x8*>(&As[rA * LDT + kb]);
      const bf16x8 a1 = *reinterpret_cast<const bf16x8*>(&As[(rA + 16) * LDT + kb]);
#pragma unroll
      for (int n = 0; n < 4; ++n) {
        const bf16x8 b = *reinterpret_cast<const bf16x8*>(&Bs[(n * 16 + (lane & 15)) * LDT + kb]);
        acc[0][n] = MFMA16(a0, b, acc[0][n]);
        acc[1][n] = MFMA16(a1, b, acc[1][n]);
      }
    }
    __syncthreads();
  }
  // C/D layout (m89-verified): col = lane&15, row = (lane>>4)*4 + reg
  float* Cp = Cpart + (size_t)blockIdx.y * N * HID;
  const int r4 = (lane >> 4) << 2, col = lane & 15;
#pragma unroll
  for (int m = 0; m < 2; ++m)
#pragma unroll
    for (int n = 0; n < 4; ++n)
#pragma unroll
      for (int r = 0; r < 4; ++r)
        Cp[(size_t)(i0 + wave * 32 + m * 16 + r4 + r) * HID + n * 16 + col] = acc[m][n][r];
}

// W1 [256][64] f32 -> W1T [64][256] bf16
__global__ void prep_w1t(const float* __restrict__ W1, bf16* __restrict__ W1T) {
  const int idx = blockIdx.x * 256 + threadIdx.x;  // 16384 total
  const int j = idx >> 8, k = idx & 255;
  W1T[idx] = (bf16)W1[k * HID + j];
}

// s1 [8192][64] f32 -> S1T [64][8192] bf16 (tile-transpose via LDS)
__global__ __launch_bounds__(256) void transpose_bf16_64(const float* __restrict__ in,
                                                         bf16* __restrict__ out) {
  __shared__ float t[64][65];
  const int i0 = blockIdx.x * 64;
  const int tid = threadIdx.x;
#pragma unroll
  for (int s = 0; s < 4; ++s) {
    const int idx = tid + s * 256;  // 1024 float4 chunks
    const int row = idx >> 4, c4 = idx & 15;
    const float4 v = *reinterpret_cast<const float4*>(&in[(size_t)(i0 + row) * HID + c4 * 4]);
    t[row][c4 * 4 + 0] = v.x; t[row][c4 * 4 + 1] = v.y;
    t[row][c4 * 4 + 2] = v.z; t[row][c4 * 4 + 3] = v.w;
  }
  __syncthreads();
#pragma unroll
  for (int s = 0; s < 2; ++s) {
    const int idx = tid + s * 256;  // 512 chunks of 8 bf16
    const int j = idx >> 3, q = idx & 7;
    bf16x8 o;
#pragma unroll
    for (int e = 0; e < 8; ++e) o[e] = (bf16)t[q * 8 + e][j];
    *reinterpret_cast<bf16x8*>(&out[(size_t)j * N + i0 + q * 8]) = o;
  }
}

// h1T[j][i] = relu(sum_s pB[s][i][j]) as bf16  (fused reduce + relu + transpose)
__global__ __launch_bounds__(256) void reduce_relu_T(const float* __restrict__ pB,
                                                     bf16* __restrict__ h1T) {
  __shared__ float t[64][65];
  const int i0 = blockIdx.x * 64;
  const int tid = threadIdx.x;
#pragma unroll
  for (int s = 0; s < 4; ++s) {
    const int idx = tid + s * 256;  // 1024 float4 chunks
    const int row = idx >> 4, c4 = idx & 15;
    const size_t off = (size_t)(i0 + row) * HID + c4 * 4;
    float4 a = {0.f, 0.f, 0.f, 0.f};
#pragma unroll
    for (int sp = 0; sp < KSPLIT; ++sp) {
      const float4 v = *reinterpret_cast<const float4*>(&pB[(size_t)sp * N * HID + off]);
      a.x += v.x; a.y += v.y; a.z += v.z; a.w += v.w;
    }
    t[row][c4 * 4 + 0] = fmaxf(a.x, 0.f); t[row][c4 * 4 + 1] = fmaxf(a.y, 0.f);
    t[row][c4 * 4 + 2] = fmaxf(a.z, 0.f); t[row][c4 * 4 + 3] = fmaxf(a.w, 0.f);
  }
  __syncthreads();
#pragma unroll
  for (int s = 0; s < 2; ++s) {
    const int idx = tid + s * 256;  // 512 chunks of 8 bf16
    const int j = idx >> 3, q = idx & 7;
    bf16x8 o;
#pragma unroll
    for (int e = 0; e < 8; ++e) o[e] = (bf16)t[q * 8 + e][j];
    *reinterpret_cast<bf16x8*>(&h1T[(size_t)j * N + i0 + q * 8]) = o;
  }
}

// t = sum_s pC[s]  (t = adj@relu(h1), [8192][64]); mu = t@W2, lv = t@W3 (f32)
__global__ __launch_bounds__(256) void reduce_w23_mulv(const float* __restrict__ pC,
                                                       const float* __restrict__ W2,
                                                       const float* __restrict__ W3,
                                                       float* __restrict__ mu,
                                                       float* __restrict__ lv) {
  __shared__ float Hs[64][65];
  __shared__ float Ws[64][128];
  const int i0 = blockIdx.x * 64;
  const int tid = threadIdx.x;
#pragma unroll
  for (int s = 0; s < 32; ++s) {  // stage W23: 8192 f32
    const int idx = tid + s * 256;
    const int c = idx >> 7, j = idx & 127;
    Ws[c][j] = (j < 64) ? W2[c * HID + j] : W3[c * HID + (j - 64)];
  }
#pragma unroll
  for (int s8 = 0; s8 < 16; ++s8) {  // reduce partials: 64x64 tile
    const int idx = tid + s8 * 256;
    const int r = idx >> 6, c = idx & 63;
    const size_t off = (size_t)(i0 + r) * HID + c;
    float a = 0.0f;
#pragma unroll
    for (int sp = 0; sp < KSPLIT; ++sp) a += pC[(size_t)sp * N * HID + off];
    Hs[r][c] = a;
  }
  __syncthreads();
  const int j = tid & 127, ih = tid >> 7;
  for (int ii = ih; ii < 64; ii += 2) {
    float a = 0.0f;
#pragma unroll
    for (int c = 0; c < 64; ++c) a += Hs[ii][c] * Ws[c][j];
    if (j < 64)
      mu[(size_t)(i0 + ii) * HID + j] = a;
    else
      lv[(size_t)(i0 + ii) * HID + (j - 64)] = a;
  }
}

// recon[i][j] = dot(mu[i,:], mu[j,:]) ; mu read as f32, cvt bf16, K=64
__global__ __launch_bounds__(256) void recon_mm(const float* __restrict__ mu,
                                                float* __restrict__ out) {
  __shared__ bf16 Am[BM * LDT];
  __shared__ bf16 Bm[BM * LDT];
  const int tid = threadIdx.x, lane = tid & 63, wave = tid >> 6;
  const int i0 = blockIdx.x * 128, j0 = blockIdx.y * 128;
  {
    const int rr = tid >> 4, c4 = tid & 15;
#pragma unroll
    for (int s = 0; s < 8; ++s) {
      const int row = rr + s * 16;
      const float4 v = *reinterpret_cast<const float4*>(&mu[(size_t)(i0 + row) * HID + c4 * 4]);
      bf16x4 o;
      o[0] = (bf16)v.x; o[1] = (bf16)v.y; o[2] = (bf16)v.z; o[3] = (bf16)v.w;
      *reinterpret_cast<bf16x4*>(&Am[row * LDT + c4 * 4]) = o;
      const float4 w = *reinterpret_cast<const float4*>(&mu[(size_t)(j0 + row) * HID + c4 * 4]);
      bf16x4 p;
      p[0] = (bf16)w.x; p[1] = (bf16)w.y; p[2] = (bf16)w.z; p[3] = (bf16)w.w;
      *reinterpret_cast<bf16x4*>(&Bm[row * LDT + c4 * 4]) = p;
    }
  }
  __syncthreads();
  f32x4 acc[2][8] = {};
  const int rA = wave * 32 + (lane & 15);
#pragma unroll
  for (int kk = 0; kk < 2; ++kk) {
    const int kb = kk * 32 + ((lane >> 4) << 3);
    const bf16x8 a0 = *reinterpret_cast<const bf16x8*>(&Am[rA * LDT + kb]);
    const bf16x8 a1 = *reinterpret_cast<const bf16x8*>(&Am[(rA + 16) * LDT + kb]);
#pragma unroll
    for (int n = 0; n < 8; ++n) {
      const bf16x8 b = *reinterpret_cast<const bf16x8*>(&Bm[(n * 16 + (lane & 15)) * LDT + kb]);
      acc[0][n] = MFMA16(a0, b, acc[0][n]);
      acc[1][n] = MFMA16(a1, b, acc[1][n]);
    }
  }
  const int r4 = (lane >> 4) << 2, c = lane & 15;
#pragma unroll
  for (int m = 0; m < 2; ++m)
#pragma unroll
    for (int n = 0; n < 8; ++n)
#pragma unroll
      for (int r = 0; r < 4; ++r)
        out[(size_t)(i0 + wave * 32 + m * 16 + r4 + r) * N + j0 + n * 16 + c] = acc[m][n][r];
}

extern "C" void kernel_launch(void* const* d_in, const int* in_sizes, int n_in, void* d_out,
                              int out_size, void* d_ws, size_t ws_size, hipStream_t stream) {
  const float* x   = (const float*)d_in[0];
  const float* adj = (const float*)d_in[1];
  const float* W1  = (const float*)d_in[2];
  const float* W2  = (const float*)d_in[3];
  const float* W3  = (const float*)d_in[4];

  float* out    = (float*)d_out;
  float* recon  = out;                          // [8192][8192]  256 MiB
  float* mu_out = out + (size_t)N * N;          // [8192][64]    (outside recon region)
  float* lv_out = mu_out + (size_t)N * HID;     // [8192][64]

  // Scratch lives inside the recon region of d_out (first 37 MiB < 256 MiB):
  // every scratch buffer is dead before recon_mm overwrites the region
  // (recon_mm reads only mu_out, which is outside it).
  char* scr    = (char*)d_out;
  bf16*  S1T   = (bf16*)(scr + 0);                      // [64][8192]     1 MB
  float* s1acc = (float*)(scr + (1u << 20));            // [8192][64]     2 MB
  bf16*  h1T   = (bf16*)(scr + (3u << 20));             // [64][8192]     1 MB
  bf16*  W1T   = (bf16*)(scr + (4u << 20));             // [64][256]      32 KB
  float* pB    = (float*)(scr + (5u << 20));            // [8][8192][64] 16 MB -> ends 21 MiB
  float* pC    = (float*)(scr + (21u << 20));           // [8][8192][64] 16 MB -> ends 37 MiB

  prep_w1t<<<64, 256, 0, stream>>>(W1, W1T);
  // s1 = x @ W1   (single split -> direct store)
  gcn_mm<<<dim3(64, 1), 256, 0, stream>>>(x, FEAT, W1T, s1acc, FEAT / BK);
  transpose_bf16_64<<<128, 256, 0, stream>>>(s1acc, S1T);
  // pB[s] = adj_slice @ s1   (adj read f32 directly, no bf16 copy)
  gcn_mm<<<dim3(64, KSPLIT), 256, 0, stream>>>(adj, N, S1T, pB, (N / KSPLIT) / BK);
  // h1T = relu(sum_s pB[s])^T  bf16
  reduce_relu_T<<<128, 256, 0, stream>>>(pB, h1T);
  // pC[s] = adj_slice @ relu(h1)   (associativity: W2/W3 applied after)
  gcn_mm<<<dim3(64, KSPLIT), 256, 0, stream>>>(adj, N, h1T, pC, (N / KSPLIT) / BK);
  // t = sum_s pC[s]; mu = t@W2, lv = t@W3
  reduce_w23_mulv<<<128, 256, 0, stream>>>(pC, W2, W3, mu_out, lv_out);
  // recon = mu @ mu^T
  recon_mm<<<dim3(64, 64), 256, 0, stream>>>(mu_out, recon);
}

// Round 7
// 281.898 us; speedup vs baseline: 1.1486x; 1.1486x over previous
//
#include <hip/hip_runtime.h>

typedef __bf16 bf16;
typedef __attribute__((ext_vector_type(4))) __bf16 bf16x4;
typedef __attribute__((ext_vector_type(8))) __bf16 bf16x8;
typedef __attribute__((ext_vector_type(4))) float f32x4;

#define MFMA16(a, b, c) __builtin_amdgcn_mfma_f32_16x16x32_bf16((a), (b), (c), 0, 0, 0)

constexpr int BM  = 128;
constexpr int BK  = 64;
constexpr int LDT = 72;  // padded LDS row stride in bf16 (144 B: 16B-aligned, row-conflict-free)

constexpr int N    = 8192;
constexpr int FEAT = 256;
constexpr int HID  = 64;
constexpr int KSPLIT = 16;

// Cpart[blockIdx.y][M][64] = A[M][Kslice] (f32, cvt->bf16 on stage) @ Bt[64][Kslice]^T (bf16)
// Software-pipelined: regs prefetch tile k+1 during tile k's MFMA phase, so the
// ~900cyc HBM latency hides under compute instead of draining at the barrier.
__global__ __launch_bounds__(256) void gcn_mm(const float* __restrict__ A, int K,
                                              const bf16* __restrict__ Bt,
                                              float* __restrict__ Cpart, int ktiles) {
  __shared__ bf16 As[BM * LDT];
  __shared__ bf16 Bs[64 * LDT];
  const int tid = threadIdx.x, lane = tid & 63, wave = tid >> 6;
  const int i0 = blockIdx.x * BM;
  const int kbase = blockIdx.y * ktiles * BK;
  const int rr = tid >> 4, c4 = tid & 15;      // A-stage: row rr+16s, 16B chunk c4
  const int bn = tid >> 2, bq = (tid & 3) * 2; // B-stage: row bn, chunks bq,bq+1

  float4 ra[8];
  bf16x8 rb0, rb1;

  auto load_tile = [&](int k0) {
#pragma unroll
    for (int s = 0; s < 8; ++s)
      ra[s] = *reinterpret_cast<const float4*>(&A[(size_t)(i0 + rr + s * 16) * K + k0 + c4 * 4]);
    rb0 = *reinterpret_cast<const bf16x8*>(&Bt[(size_t)bn * K + k0 + bq * 8]);
    rb1 = *reinterpret_cast<const bf16x8*>(&Bt[(size_t)bn * K + k0 + bq * 8 + 8]);
  };

  f32x4 acc[2][4] = {};
  load_tile(kbase);
  for (int kt = 0; kt < ktiles; ++kt) {
    // write phase: cvt regs -> LDS
#pragma unroll
    for (int s = 0; s < 8; ++s) {
      bf16x4 o;
      o[0] = (bf16)ra[s].x; o[1] = (bf16)ra[s].y; o[2] = (bf16)ra[s].z; o[3] = (bf16)ra[s].w;
      *reinterpret_cast<bf16x4*>(&As[(rr + s * 16) * LDT + c4 * 4]) = o;
    }
    *reinterpret_cast<bf16x8*>(&Bs[bn * LDT + bq * 8]) = rb0;
    *reinterpret_cast<bf16x8*>(&Bs[bn * LDT + bq * 8 + 8]) = rb1;
    __syncthreads();
    if (kt + 1 < ktiles) load_tile(kbase + (kt + 1) * BK);  // async: consumed next iter
    const int rA = wave * 32 + (lane & 15);
#pragma unroll
    for (int kk = 0; kk < 2; ++kk) {
      const int kb = kk * 32 + ((lane >> 4) << 3);
      const bf16x8 a0 = *reinterpret_cast<const bf16x8*>(&As[rA * LDT + kb]);
      const bf16x8 a1 = *reinterpret_cast<const bf16x8*>(&As[(rA + 16) * LDT + kb]);
#pragma unroll
      for (int n = 0; n < 4; ++n) {
        const bf16x8 b = *reinterpret_cast<const bf16x8*>(&Bs[(n * 16 + (lane & 15)) * LDT + kb]);
        acc[0][n] = MFMA16(a0, b, acc[0][n]);
        acc[1][n] = MFMA16(a1, b, acc[1][n]);
      }
    }
    __syncthreads();
  }
  // C/D layout (m89-verified): col = lane&15, row = (lane>>4)*4 + reg
  float* Cp = Cpart + (size_t)blockIdx.y * N * HID;
  const int r4 = (lane >> 4) << 2, col = lane & 15;
#pragma unroll
  for (int m = 0; m < 2; ++m)
#pragma unroll
    for (int n = 0; n < 4; ++n)
#pragma unroll
      for (int r = 0; r < 4; ++r)
        Cp[(size_t)(i0 + wave * 32 + m * 16 + r4 + r) * HID + n * 16 + col] = acc[m][n][r];
}

// W1 [256][64] f32 -> W1T [64][256] bf16
__global__ void prep_w1t(const float* __restrict__ W1, bf16* __restrict__ W1T) {
  const int idx = blockIdx.x * 256 + threadIdx.x;  // 16384 total
  const int j = idx >> 8, k = idx & 255;
  W1T[idx] = (bf16)W1[k * HID + j];
}

// s1 [8192][64] f32 -> S1T [64][8192] bf16 (tile-transpose via LDS)
__global__ __launch_bounds__(256) void transpose_bf16_64(const float* __restrict__ in,
                                                         bf16* __restrict__ out) {
  __shared__ float t[64][65];
  const int i0 = blockIdx.x * 64;
  const int tid = threadIdx.x;
#pragma unroll
  for (int s = 0; s < 4; ++s) {
    const int idx = tid + s * 256;  // 1024 float4 chunks
    const int row = idx >> 4, c4 = idx & 15;
    const float4 v = *reinterpret_cast<const float4*>(&in[(size_t)(i0 + row) * HID + c4 * 4]);
    t[row][c4 * 4 + 0] = v.x; t[row][c4 * 4 + 1] = v.y;
    t[row][c4 * 4 + 2] = v.z; t[row][c4 * 4 + 3] = v.w;
  }
  __syncthreads();
#pragma unroll
  for (int s = 0; s < 2; ++s) {
    const int idx = tid + s * 256;  // 512 chunks of 8 bf16
    const int j = idx >> 3, q = idx & 7;
    bf16x8 o;
#pragma unroll
    for (int e = 0; e < 8; ++e) o[e] = (bf16)t[q * 8 + e][j];
    *reinterpret_cast<bf16x8*>(&out[(size_t)j * N + i0 + q * 8]) = o;
  }
}

// h1T[j][i] = relu(sum_s pB[s][i][j]) as bf16  (fused reduce + relu + transpose)
__global__ __launch_bounds__(256) void reduce_relu_T(const float* __restrict__ pB,
                                                     bf16* __restrict__ h1T) {
  __shared__ float t[64][65];
  const int i0 = blockIdx.x * 64;
  const int tid = threadIdx.x;
#pragma unroll
  for (int s = 0; s < 4; ++s) {
    const int idx = tid + s * 256;  // 1024 float4 chunks
    const int row = idx >> 4, c4 = idx & 15;
    const size_t off = (size_t)(i0 + row) * HID + c4 * 4;
    float4 a = {0.f, 0.f, 0.f, 0.f};
#pragma unroll
    for (int sp = 0; sp < KSPLIT; ++sp) {
      const float4 v = *reinterpret_cast<const float4*>(&pB[(size_t)sp * N * HID + off]);
      a.x += v.x; a.y += v.y; a.z += v.z; a.w += v.w;
    }
    t[row][c4 * 4 + 0] = fmaxf(a.x, 0.f); t[row][c4 * 4 + 1] = fmaxf(a.y, 0.f);
    t[row][c4 * 4 + 2] = fmaxf(a.z, 0.f); t[row][c4 * 4 + 3] = fmaxf(a.w, 0.f);
  }
  __syncthreads();
#pragma unroll
  for (int s = 0; s < 2; ++s) {
    const int idx = tid + s * 256;  // 512 chunks of 8 bf16
    const int j = idx >> 3, q = idx & 7;
    bf16x8 o;
#pragma unroll
    for (int e = 0; e < 8; ++e) o[e] = (bf16)t[q * 8 + e][j];
    *reinterpret_cast<bf16x8*>(&h1T[(size_t)j * N + i0 + q * 8]) = o;
  }
}

// t = sum_s pC[s]  (t = adj@relu(h1), [8192][64]); mu = t@W2, lv = t@W3 (f32)
__global__ __launch_bounds__(256) void reduce_w23_mulv(const float* __restrict__ pC,
                                                       const float* __restrict__ W2,
                                                       const float* __restrict__ W3,
                                                       float* __restrict__ mu,
                                                       float* __restrict__ lv) {
  __shared__ float Hs[64][65];
  __shared__ float Ws[64][128];
  const int i0 = blockIdx.x * 64;
  const int tid = threadIdx.x;
#pragma unroll
  for (int s = 0; s < 32; ++s) {  // stage W23: 8192 f32
    const int idx = tid + s * 256;
    const int c = idx >> 7, j = idx & 127;
    Ws[c][j] = (j < 64) ? W2[c * HID + j] : W3[c * HID + (j - 64)];
  }
#pragma unroll
  for (int s8 = 0; s8 < 16; ++s8) {  // reduce partials: 64x64 tile
    const int idx = tid + s8 * 256;
    const int r = idx >> 6, c = idx & 63;
    const size_t off = (size_t)(i0 + r) * HID + c;
    float a = 0.0f;
#pragma unroll
    for (int sp = 0; sp < KSPLIT; ++sp) a += pC[(size_t)sp * N * HID + off];
    Hs[r][c] = a;
  }
  __syncthreads();
  const int j = tid & 127, ih = tid >> 7;
  for (int ii = ih; ii < 64; ii += 2) {
    float a = 0.0f;
#pragma unroll
    for (int c = 0; c < 64; ++c) a += Hs[ii][c] * Ws[c][j];
    if (j < 64)
      mu[(size_t)(i0 + ii) * HID + j] = a;
    else
      lv[(size_t)(i0 + ii) * HID + (j - 64)] = a;
  }
}

// recon[i][j] = dot(mu[i,:], mu[j,:]) ; mu read as f32, cvt bf16, K=64
__global__ __launch_bounds__(256) void recon_mm(const float* __restrict__ mu,
                                                float* __restrict__ out) {
  __shared__ bf16 Am[BM * LDT];
  __shared__ bf16 Bm[BM * LDT];
  const int tid = threadIdx.x, lane = tid & 63, wave = tid >> 6;
  const int i0 = blockIdx.x * 128, j0 = blockIdx.y * 128;
  {
    const int rr = tid >> 4, c4 = tid & 15;
#pragma unroll
    for (int s = 0; s < 8; ++s) {
      const int row = rr + s * 16;
      const float4 v = *reinterpret_cast<const float4*>(&mu[(size_t)(i0 + row) * HID + c4 * 4]);
      bf16x4 o;
      o[0] = (bf16)v.x; o[1] = (bf16)v.y; o[2] = (bf16)v.z; o[3] = (bf16)v.w;
      *reinterpret_cast<bf16x4*>(&Am[row * LDT + c4 * 4]) = o;
      const float4 w = *reinterpret_cast<const float4*>(&mu[(size_t)(j0 + row) * HID + c4 * 4]);
      bf16x4 p;
      p[0] = (bf16)w.x; p[1] = (bf16)w.y; p[2] = (bf16)w.z; p[3] = (bf16)w.w;
      *reinterpret_cast<bf16x4*>(&Bm[row * LDT + c4 * 4]) = p;
    }
  }
  __syncthreads();
  f32x4 acc[2][8] = {};
  const int rA = wave * 32 + (lane & 15);
#pragma unroll
  for (int kk = 0; kk < 2; ++kk) {
    const int kb = kk * 32 + ((lane >> 4) << 3);
    const bf16x8 a0 = *reinterpret_cast<const bf16x8*>(&Am[rA * LDT + kb]);
    const bf16x8 a1 = *reinterpret_cast<const bf16x8*>(&Am[(rA + 16) * LDT + kb]);
#pragma unroll
    for (int n = 0; n < 8; ++n) {
      const bf16x8 b = *reinterpret_cast<const bf16x8*>(&Bm[(n * 16 + (lane & 15)) * LDT + kb]);
      acc[0][n] = MFMA16(a0, b, acc[0][n]);
      acc[1][n] = MFMA16(a1, b, acc[1][n]);
    }
  }
  const int r4 = (lane >> 4) << 2, c = lane & 15;
#pragma unroll
  for (int m = 0; m < 2; ++m)
#pragma unroll
    for (int n = 0; n < 8; ++n)
#pragma unroll
      for (int r = 0; r < 4; ++r)
        out[(size_t)(i0 + wave * 32 + m * 16 + r4 + r) * N + j0 + n * 16 + c] = acc[m][n][r];
}

extern "C" void kernel_launch(void* const* d_in, const int* in_sizes, int n_in, void* d_out,
                              int out_size, void* d_ws, size_t ws_size, hipStream_t stream) {
  const float* x   = (const float*)d_in[0];
  const float* adj = (const float*)d_in[1];
  const float* W1  = (const float*)d_in[2];
  const float* W2  = (const float*)d_in[3];
  const float* W3  = (const float*)d_in[4];

  float* out    = (float*)d_out;
  float* recon  = out;                          // [8192][8192]  256 MiB
  float* mu_out = out + (size_t)N * N;          // [8192][64]    (outside recon region)
  float* lv_out = mu_out + (size_t)N * HID;     // [8192][64]

  // Scratch lives inside the recon region of d_out (first 69 MiB < 256 MiB):
  // every scratch buffer is dead before recon_mm overwrites the region
  // (recon_mm reads only mu_out, which is outside it).
  char* scr    = (char*)d_out;
  bf16*  S1T   = (bf16*)(scr + 0);                      // [64][8192]      1 MB
  float* s1acc = (float*)(scr + (1u << 20));            // [8192][64]      2 MB
  bf16*  h1T   = (bf16*)(scr + (3u << 20));             // [64][8192]      1 MB
  bf16*  W1T   = (bf16*)(scr + (4u << 20));             // [64][256]       32 KB
  float* pB    = (float*)(scr + (5u << 20));            // [16][8192][64] 32 MB -> ends 37 MiB
  float* pC    = (float*)(scr + (37u << 20));           // [16][8192][64] 32 MB -> ends 69 MiB

  prep_w1t<<<64, 256, 0, stream>>>(W1, W1T);
  // s1 = x @ W1   (single split -> direct store)
  gcn_mm<<<dim3(64, 1), 256, 0, stream>>>(x, FEAT, W1T, s1acc, FEAT / BK);
  transpose_bf16_64<<<128, 256, 0, stream>>>(s1acc, S1T);
  // pB[s] = adj_slice @ s1   (adj read f32 directly)
  gcn_mm<<<dim3(64, KSPLIT), 256, 0, stream>>>(adj, N, S1T, pB, (N / KSPLIT) / BK);
  // h1T = relu(sum_s pB[s])^T  bf16
  reduce_relu_T<<<128, 256, 0, stream>>>(pB, h1T);
  // pC[s] = adj_slice @ relu(h1)   (associativity: W2/W3 applied after)
  gcn_mm<<<dim3(64, KSPLIT), 256, 0, stream>>>(adj, N, h1T, pC, (N / KSPLIT) / BK);
  // t = sum_s pC[s]; mu = t@W2, lv = t@W3
  reduce_w23_mulv<<<128, 256, 0, stream>>>(pC, W2, W3, mu_out, lv_out);
  // recon = mu @ mu^T
  recon_mm<<<dim3(64, 64), 256, 0, stream>>>(mu_out, recon);
}